// Round 2
// baseline (1243.697 us; speedup 1.0000x reference)
//
#include <hip/hip_runtime.h>

// Problem constants (B=1)
#define T_    8
#define C_    64
#define H_    256
#define W_    256
#define HD_   4
#define CH_   16     // C_/HD_
#define PS_   7
#define Q_    32768
#define KTOT_ 15
#define K_    10
#define HW_   (H_*W_)

// ---------------------------------------------------------------------------
// Kernel 1: transpose vid [T][C][H][W] -> vidT [T][H][W][C]  (channels-last)
// ---------------------------------------------------------------------------
__global__ __launch_bounds__(256) void transpose_vid_kernel(
    const float* __restrict__ vid, float* __restrict__ vidT) {
  __shared__ float tile[64][65];
  const int b  = blockIdx.x;       // grid = T_*H_*(W_/64) = 8192
  const int wt = b & 3;
  const int h  = (b >> 2) & (H_ - 1);
  const int t  = b >> 10;
  const int w0 = wt * 64;

  const float* src = vid + (size_t)t * C_ * HW_ + (size_t)h * W_ + w0;
  const int wq = (threadIdx.x & 15) * 4;
  const int c0 = threadIdx.x >> 4;
  #pragma unroll
  for (int i = 0; i < 4; ++i) {
    const int c = c0 + i * 16;
    const float4 v = *reinterpret_cast<const float4*>(src + (size_t)c * HW_ + wq);
    tile[c][wq + 0] = v.x; tile[c][wq + 1] = v.y;
    tile[c][wq + 2] = v.z; tile[c][wq + 3] = v.w;
  }
  __syncthreads();

  float* dst = vidT + (((size_t)t * H_ + h) * W_ + w0) * C_;
  const int cq = (threadIdx.x & 15) * 4;
  const int w1 = threadIdx.x >> 4;
  #pragma unroll
  for (int i = 0; i < 4; ++i) {
    const int w = w1 + i * 16;
    float4 v;
    v.x = tile[cq + 0][w]; v.y = tile[cq + 1][w];
    v.z = tile[cq + 2][w]; v.w = tile[cq + 3][w];
    *reinterpret_cast<float4*>(dst + (size_t)w * C_ + cq) = v;
  }
}

// ---------------------------------------------------------------------------
// Kernel 2 (channels-last): float4-per-lane, max MLP.
// Block = 448 threads (7 waves), one q per block. Wave = patch row pi.
// Lane = psub*16 + hd*4 + cgrp:
//   load0: pj = psub      (4 positions x 64 ch = 1 KB / wave-load)
//   load1: pj = 4 + psub  (exec-masked to psub<3 -> 768 B, zero overfetch)
// Full K=10 unroll: 20 float4 loads in flight per wave (~17.5 KB).
// Stores: 1 KB fully coalesced float4 per wave (+768 B masked).
// ---------------------------------------------------------------------------
__global__ __launch_bounds__(448, 4) void wpsum_tr_kernel(
    const float* __restrict__ vsrc,     // vidT channels-last
    const float* __restrict__ dists,
    const int*   __restrict__ inds,
    float*       __restrict__ out) {
  const int q   = blockIdx.x;
  const int tid = threadIdx.x;

  __shared__ int   s_off[HD_][K_];
  __shared__ float s_w[HD_][K_];
  if (tid < HD_ * K_) {
    const int hd = tid / K_, k = tid % K_;
    const int* ip = inds + (((size_t)hd * Q_ + q) * KTOT_ + k) * 3;
    s_off[hd][k] = ((ip[0] * H_ + ip[1]) * W_ + ip[2]) * C_ + hd * CH_;
    s_w[hd][k]   = dists[((size_t)hd * Q_ + q) * KTOT_ + k];
  }
  __syncthreads();

  const int lane = tid & 63;
  const int pi   = tid >> 6;          // patch row 0..6
  const int cgrp = lane & 3;          // float4 group within head (4 ch)
  const int hd   = (lane >> 2) & 3;
  const int psub = lane >> 4;         // 0..3
  const bool p3  = (psub < 3);
  const int lconst = pi * (W_ * C_) + psub * C_ + cgrp * 4;

  int   off[K_];
  float wk[K_];
  #pragma unroll
  for (int k = 0; k < K_; ++k) {
    off[k] = s_off[hd][k] + lconst;
    wk[k]  = s_w[hd][k];
  }

  float4 a0[K_], a1[K_];
  #pragma unroll
  for (int k = 0; k < K_; ++k)
    a0[k] = *reinterpret_cast<const float4*>(vsrc + (size_t)off[k]);
  if (p3) {
    #pragma unroll
    for (int k = 0; k < K_; ++k)
      a1[k] = *reinterpret_cast<const float4*>(vsrc + (size_t)off[k] + 4 * C_);
  } else {
    #pragma unroll
    for (int k = 0; k < K_; ++k)
      a1[k] = make_float4(0.f, 0.f, 0.f, 0.f);
  }

  float4 acc0 = make_float4(0.f, 0.f, 0.f, 0.f);
  float4 acc1 = make_float4(0.f, 0.f, 0.f, 0.f);
  #pragma unroll
  for (int k = 0; k < K_; ++k) {
    acc0.x = fmaf(wk[k], a0[k].x, acc0.x);
    acc0.y = fmaf(wk[k], a0[k].y, acc0.y);
    acc0.z = fmaf(wk[k], a0[k].z, acc0.z);
    acc0.w = fmaf(wk[k], a0[k].w, acc0.w);
    acc1.x = fmaf(wk[k], a1[k].x, acc1.x);
    acc1.y = fmaf(wk[k], a1[k].y, acc1.y);
    acc1.z = fmaf(wk[k], a1[k].z, acc1.z);
    acc1.w = fmaf(wk[k], a1[k].w, acc1.w);
  }

  float4* ob = reinterpret_cast<float4*>(
      out + ((size_t)q * (PS_ * PS_) + (size_t)pi * PS_) * (HD_ * CH_));
  ob[lane] = acc0;                    // pj 0..3
  if (p3) ob[64 + lane] = acc1;       // pj 4..6
}

// ---------------------------------------------------------------------------
// Fallback (native layout), only used if ws can't hold vidT.
// ---------------------------------------------------------------------------
__global__ __launch_bounds__(448) void wpsum_fallback_kernel(
    const float* __restrict__ vid,
    const float* __restrict__ dists,
    const int*   __restrict__ inds,
    float*       __restrict__ out) {
  const int q   = blockIdx.x;
  const int tid = threadIdx.x;

  __shared__ int   s_off[HD_][K_];
  __shared__ float s_w[HD_][K_];
  if (tid < HD_ * K_) {
    const int hd = tid / K_, k = tid % K_;
    const int* ip = inds + (((size_t)hd * Q_ + q) * KTOT_ + k) * 3;
    s_off[hd][k] = ((ip[0] * C_ + hd * CH_) * H_ + ip[1]) * W_ + ip[2];
    s_w[hd][k]   = dists[((size_t)hd * Q_ + q) * KTOT_ + k];
  }
  __syncthreads();

  const int lane = tid & 63;
  const int pi   = tid >> 6;
  const int hd   = lane >> 4;
  const int c    = lane & 15;

  float wk[K_]; int off[K_];
  #pragma unroll
  for (int k = 0; k < K_; ++k) {
    wk[k]  = s_w[hd][k];
    off[k] = s_off[hd][k] + c * HW_;
  }
  #pragma unroll
  for (int pj = 0; pj < PS_; ++pj) {
    const int d = pi * W_ + pj;
    float acc = 0.f;
    #pragma unroll
    for (int k = 0; k < K_; ++k)
      acc = fmaf(wk[k], vid[(size_t)(off[k] + d)], acc);
    out[((size_t)q * (PS_ * PS_) + pi * PS_ + pj) * (HD_ * CH_) + lane] = acc;
  }
}

// ---------------------------------------------------------------------------
extern "C" void kernel_launch(void* const* d_in, const int* in_sizes, int n_in,
                              void* d_out, int out_size, void* d_ws, size_t ws_size,
                              hipStream_t stream) {
  const float* vid   = (const float*)d_in[0];
  const float* dists = (const float*)d_in[1];
  const int*   inds  = (const int*)d_in[2];
  float*       out   = (float*)d_out;

  const size_t need = (size_t)T_ * C_ * HW_ * sizeof(float);  // 128 MiB
  if (ws_size >= need) {
    float* vidT = (float*)d_ws;
    transpose_vid_kernel<<<T_ * H_ * (W_ / 64), 256, 0, stream>>>(vid, vidT);
    wpsum_tr_kernel<<<Q_, 448, 0, stream>>>(vidT, dists, inds, out);
  } else {
    wpsum_fallback_kernel<<<Q_, 448, 0, stream>>>(vid, dists, inds, out);
  }
}

// Round 3
// 490.846 us; speedup vs baseline: 2.5338x; 2.5338x over previous
//
#include <hip/hip_runtime.h>
#include <hip/hip_fp16.h>

// Problem constants (B=1)
#define T_    8
#define C_    64
#define H_    256
#define W_    256
#define HD_   4
#define CH_   16     // C_/HD_
#define PS_   7
#define Q_    32768
#define KTOT_ 15
#define K_    10
#define HW_   (H_*W_)

// ---------------------------------------------------------------------------
// Kernel 1: transpose+convert vid [T][C][H][W] f32 -> vidP [HD][T][H][W][CH] fp16
// Per-head channels-last: one gathered head-pixel = 16ch x 2B = 32B contiguous.
// ---------------------------------------------------------------------------
__global__ __launch_bounds__(256) void transcvt_kernel(
    const float* __restrict__ vid, __half* __restrict__ vidP) {
  __shared__ float tile[64][65];
  const int b  = blockIdx.x;       // grid = T_*H_*(W_/64) = 8192
  const int wt = b & 3;
  const int h  = (b >> 2) & (H_ - 1);
  const int t  = b >> 10;
  const int w0 = wt * 64;

  // Load 64ch x 64w tile, coalesced along w.
  const float* src = vid + (size_t)t * C_ * HW_ + (size_t)h * W_ + w0;
  const int wq = (threadIdx.x & 15) * 4;
  const int c0 = threadIdx.x >> 4;
  #pragma unroll
  for (int i = 0; i < 4; ++i) {
    const int c = c0 + i * 16;
    const float4 v = *reinterpret_cast<const float4*>(src + (size_t)c * HW_ + wq);
    tile[c][wq + 0] = v.x; tile[c][wq + 1] = v.y;
    tile[c][wq + 2] = v.z; tile[c][wq + 3] = v.w;
  }
  __syncthreads();

  // Store fp16, coalesced along (within-head channel, w) per head.
  const int cq = (threadIdx.x & 3) * 4;   // within-head channel quad 0,4,8,12
  const int w  = threadIdx.x >> 2;        // 0..63
  #pragma unroll
  for (int hd = 0; hd < HD_; ++hd) {
    ushort4 pk;
    pk.x = __half_as_ushort(__float2half_rn(tile[hd * CH_ + cq + 0][w]));
    pk.y = __half_as_ushort(__float2half_rn(tile[hd * CH_ + cq + 1][w]));
    pk.z = __half_as_ushort(__float2half_rn(tile[hd * CH_ + cq + 2][w]));
    pk.w = __half_as_ushort(__float2half_rn(tile[hd * CH_ + cq + 3][w]));
    __half* dst = vidP +
        ((((size_t)hd * T_ + t) * H_ + h) * W_ + w0 + w) * CH_ + cq;
    *reinterpret_cast<ushort4*>(dst) = pk;
  }
}

// ---------------------------------------------------------------------------
// Kernel 2: fp16 gather + f32 accumulate.
// Block = 448 threads (7 waves), one q. Wave pi owns patch row pi.
// Active lanes 0..55: lane = hd*14 + psub*2 + hv
//   -> loads 16B = 8 fp16 ch (hv selects low/high 8 of the head's 16).
// Per (k, wave) load: 4 heads x 7 px x 32B = 896B used, rows contiguous.
// K=10 fully unrolled: 10 x 16B loads in flight per lane.
// ---------------------------------------------------------------------------
__global__ __launch_bounds__(448) void wpsum_h_kernel(
    const __half* __restrict__ vsrc,    // vidP per-head channels-last
    const float* __restrict__ dists,
    const int*   __restrict__ inds,
    float*       __restrict__ out) {
  const int q   = blockIdx.x;
  const int tid = threadIdx.x;

  __shared__ int   s_off[HD_][K_];
  __shared__ float s_w[HD_][K_];
  if (tid < HD_ * K_) {
    const int hd = tid / K_, k = tid % K_;
    const int* ip = inds + (((size_t)hd * Q_ + q) * KTOT_ + k) * 3;
    s_off[hd][k] = ((((hd * T_ + ip[0]) * H_ + ip[1]) * W_) + ip[2]) * CH_;
    s_w[hd][k]   = dists[((size_t)hd * Q_ + q) * KTOT_ + k];
  }
  __syncthreads();

  const int lane = tid & 63;
  const int pi   = tid >> 6;            // patch row 0..6
  const bool act = lane < 56;
  const int hd   = act ? (lane / 14) : 0;
  const int rem  = lane - hd * 14;
  const int psub = act ? (rem >> 1) : 0;
  const int hv   = rem & 1;
  const int lconst = (pi * W_ + psub) * CH_ + hv * 8;

  float wk[K_]; int off[K_];
  #pragma unroll
  for (int k = 0; k < K_; ++k) {
    wk[k]  = s_w[hd][k];
    off[k] = s_off[hd][k] + lconst;
  }

  float4 a[K_];
  if (act) {
    #pragma unroll
    for (int k = 0; k < K_; ++k)
      a[k] = *reinterpret_cast<const float4*>(vsrc + (size_t)off[k]);
  } else {
    #pragma unroll
    for (int k = 0; k < K_; ++k)
      a[k] = make_float4(0.f, 0.f, 0.f, 0.f);
  }

  float acc[8] = {0.f, 0.f, 0.f, 0.f, 0.f, 0.f, 0.f, 0.f};
  #pragma unroll
  for (int k = 0; k < K_; ++k) {
    const __half2* hp = reinterpret_cast<const __half2*>(&a[k]);
    #pragma unroll
    for (int j = 0; j < 4; ++j) {
      const float2 f = __half22float2(hp[j]);
      acc[2 * j + 0] = fmaf(wk[k], f.x, acc[2 * j + 0]);
      acc[2 * j + 1] = fmaf(wk[k], f.y, acc[2 * j + 1]);
    }
  }

  if (act) {
    float* ob = out + ((size_t)q * (PS_ * PS_) + pi * PS_ + psub) * (HD_ * CH_)
                    + hd * CH_ + hv * 8;
    *reinterpret_cast<float4*>(ob + 0) = make_float4(acc[0], acc[1], acc[2], acc[3]);
    *reinterpret_cast<float4*>(ob + 4) = make_float4(acc[4], acc[5], acc[6], acc[7]);
  }
}

// ---------------------------------------------------------------------------
// Fallback (native layout, f32), only if ws can't hold vidP.
// ---------------------------------------------------------------------------
__global__ __launch_bounds__(448) void wpsum_fallback_kernel(
    const float* __restrict__ vid,
    const float* __restrict__ dists,
    const int*   __restrict__ inds,
    float*       __restrict__ out) {
  const int q   = blockIdx.x;
  const int tid = threadIdx.x;

  __shared__ int   s_off[HD_][K_];
  __shared__ float s_w[HD_][K_];
  if (tid < HD_ * K_) {
    const int hd = tid / K_, k = tid % K_;
    const int* ip = inds + (((size_t)hd * Q_ + q) * KTOT_ + k) * 3;
    s_off[hd][k] = ((ip[0] * C_ + hd * CH_) * H_ + ip[1]) * W_ + ip[2];
    s_w[hd][k]   = dists[((size_t)hd * Q_ + q) * KTOT_ + k];
  }
  __syncthreads();

  const int lane = tid & 63;
  const int pi   = tid >> 6;
  const int hd   = lane >> 4;
  const int c    = lane & 15;

  float wk[K_]; int off[K_];
  #pragma unroll
  for (int k = 0; k < K_; ++k) {
    wk[k]  = s_w[hd][k];
    off[k] = s_off[hd][k] + c * HW_;
  }
  #pragma unroll
  for (int pj = 0; pj < PS_; ++pj) {
    const int d = pi * W_ + pj;
    float acc = 0.f;
    #pragma unroll
    for (int k = 0; k < K_; ++k)
      acc = fmaf(wk[k], vid[(size_t)(off[k] + d)], acc);
    out[((size_t)q * (PS_ * PS_) + pi * PS_ + pj) * (HD_ * CH_) + lane] = acc;
  }
}

// ---------------------------------------------------------------------------
extern "C" void kernel_launch(void* const* d_in, const int* in_sizes, int n_in,
                              void* d_out, int out_size, void* d_ws, size_t ws_size,
                              hipStream_t stream) {
  const float* vid   = (const float*)d_in[0];
  const float* dists = (const float*)d_in[1];
  const int*   inds  = (const int*)d_in[2];
  float*       out   = (float*)d_out;

  const size_t need = (size_t)HD_ * T_ * HW_ * CH_ * sizeof(__half);  // 64 MiB
  if (ws_size >= need) {
    __half* vidP = (__half*)d_ws;
    transcvt_kernel<<<T_ * H_ * (W_ / 64), 256, 0, stream>>>(vid, vidP);
    wpsum_h_kernel<<<Q_, 448, 0, stream>>>(vidP, dists, inds, out);
  } else {
    wpsum_fallback_kernel<<<Q_, 448, 0, stream>>>(vid, dists, inds, out);
  }
}

// Round 4
// 489.622 us; speedup vs baseline: 2.5401x; 1.0025x over previous
//
#include <hip/hip_runtime.h>
#include <hip/hip_fp16.h>

// Problem constants (B=1)
#define T_    8
#define C_    64
#define H_    256
#define W_    256
#define HD_   4
#define CH_   16     // C_/HD_
#define PS_   7
#define Q_    32768
#define KTOT_ 15
#define K_    10
#define HW_   (H_*W_)

typedef float f32x4 __attribute__((ext_vector_type(4)));

// ---------------------------------------------------------------------------
// Kernel 1: transpose+convert vid [T][C][H][W] f32 -> vidP [HD][T][H][W][CH] fp16
// ---------------------------------------------------------------------------
__global__ __launch_bounds__(256) void transcvt_kernel(
    const float* __restrict__ vid, __half* __restrict__ vidP) {
  __shared__ float tile[64][65];
  const int b  = blockIdx.x;       // grid = T_*H_*(W_/64) = 8192
  const int wt = b & 3;
  const int h  = (b >> 2) & (H_ - 1);
  const int t  = b >> 10;
  const int w0 = wt * 64;

  const float* src = vid + (size_t)t * C_ * HW_ + (size_t)h * W_ + w0;
  const int wq = (threadIdx.x & 15) * 4;
  const int c0 = threadIdx.x >> 4;
  #pragma unroll
  for (int i = 0; i < 4; ++i) {
    const int c = c0 + i * 16;
    const float4 v = *reinterpret_cast<const float4*>(src + (size_t)c * HW_ + wq);
    tile[c][wq + 0] = v.x; tile[c][wq + 1] = v.y;
    tile[c][wq + 2] = v.z; tile[c][wq + 3] = v.w;
  }
  __syncthreads();

  const int cq = (threadIdx.x & 3) * 4;   // within-head channel quad
  const int w  = threadIdx.x >> 2;        // 0..63
  #pragma unroll
  for (int hd = 0; hd < HD_; ++hd) {
    ushort4 pk;
    pk.x = __half_as_ushort(__float2half_rn(tile[hd * CH_ + cq + 0][w]));
    pk.y = __half_as_ushort(__float2half_rn(tile[hd * CH_ + cq + 1][w]));
    pk.z = __half_as_ushort(__float2half_rn(tile[hd * CH_ + cq + 2][w]));
    pk.w = __half_as_ushort(__float2half_rn(tile[hd * CH_ + cq + 3][w]));
    __half* dst = vidP +
        ((((size_t)hd * T_ + t) * H_ + h) * W_ + w0 + w) * CH_ + cq;
    *reinterpret_cast<ushort4*>(dst) = pk;
  }
}

// ---------------------------------------------------------------------------
// Kernel 2: fp16 gather + f32 accumulate, (t,hi)-sorted chunked gathers,
// non-temporal output stores.
// Block = 448 threads (7 waves), one q. Wave pi owns patch row pi.
// Active lanes 0..55: lane = hd*14 + psub*2 + hv -> 16B = 8 fp16 channels.
// ---------------------------------------------------------------------------
__global__ __launch_bounds__(448) void wpsum_h_kernel(
    const __half* __restrict__ vsrc,    // vidP per-head channels-last
    const float* __restrict__ dists,
    const int*   __restrict__ inds,
    float*       __restrict__ out) {
  const int q   = blockIdx.x;
  const int tid = threadIdx.x;

  __shared__ int   s_key[HD_][K_];
  __shared__ int   s_toff[HD_][K_];
  __shared__ float s_tw[HD_][K_];
  __shared__ int   s_off[HD_][K_];
  __shared__ float s_w[HD_][K_];

  if (tid < HD_ * K_) {
    const int hd = tid / K_, k = tid % K_;
    const int* ip = inds + (((size_t)hd * Q_ + q) * KTOT_ + k) * 3;
    const int t = ip[0], hi = ip[1], wi = ip[2];
    s_key[hd][k]  = (t << 8) | hi;
    s_toff[hd][k] = (((hd * T_ + t) * H_ + hi) * W_ + wi) * CH_;
    s_tw[hd][k]   = dists[((size_t)hd * Q_ + q) * KTOT_ + k];
  }
  __syncthreads();
  // Parallel rank-sort by (t,hi): r = # of entries with smaller key (ties by k).
  if (tid < HD_ * K_) {
    const int hd = tid / K_, k = tid % K_;
    const int key = s_key[hd][k];
    int r = 0;
    #pragma unroll
    for (int j = 0; j < K_; ++j) {
      const int kj = s_key[hd][j];
      r += (kj < key) || (kj == key && j < k);
    }
    s_off[hd][r] = s_toff[hd][k];
    s_w[hd][r]   = s_tw[hd][k];
  }
  __syncthreads();

  const int lane = tid & 63;
  const int pi   = tid >> 6;            // patch row 0..6
  const bool act = lane < 56;
  const int hd   = act ? (lane / 14) : 0;
  const int rem  = lane - hd * 14;
  const int psub = rem >> 1;
  const int hv   = rem & 1;
  const int lconst = (pi * W_ + psub) * CH_ + hv * 8;

  float acc[8] = {0.f, 0.f, 0.f, 0.f, 0.f, 0.f, 0.f, 0.f};

  // 5 sequential chunks of 2 gathers, in sorted (t,hi) order. Rolled loop
  // enforces temporal ordering (the cross-block L2 locality mechanism).
  #pragma unroll 1
  for (int c = 0; c < K_ / 2; ++c) {
    const float w0 = s_w[hd][2 * c + 0];
    const float w1 = s_w[hd][2 * c + 1];
    f32x4 a0 = {0.f, 0.f, 0.f, 0.f}, a1 = {0.f, 0.f, 0.f, 0.f};
    if (act) {
      a0 = *reinterpret_cast<const f32x4*>(
          vsrc + (size_t)(s_off[hd][2 * c + 0] + lconst));
      a1 = *reinterpret_cast<const f32x4*>(
          vsrc + (size_t)(s_off[hd][2 * c + 1] + lconst));
    }
    const __half2* h0 = reinterpret_cast<const __half2*>(&a0);
    const __half2* h1 = reinterpret_cast<const __half2*>(&a1);
    #pragma unroll
    for (int j = 0; j < 4; ++j) {
      const float2 f0 = __half22float2(h0[j]);
      const float2 f1 = __half22float2(h1[j]);
      acc[2 * j + 0] = fmaf(w0, f0.x, acc[2 * j + 0]);
      acc[2 * j + 1] = fmaf(w0, f0.y, acc[2 * j + 1]);
      acc[2 * j + 0] = fmaf(w1, f1.x, acc[2 * j + 0]);
      acc[2 * j + 1] = fmaf(w1, f1.y, acc[2 * j + 1]);
    }
  }

  if (act) {
    float* ob = out + ((size_t)q * (PS_ * PS_) + pi * PS_ + psub) * (HD_ * CH_)
                    + hd * CH_ + hv * 8;
    f32x4 v0 = {acc[0], acc[1], acc[2], acc[3]};
    f32x4 v1 = {acc[4], acc[5], acc[6], acc[7]};
    // Non-temporal: output is write-once, never read -> don't evict the
    // gather working set from L2.
    __builtin_nontemporal_store(v0, reinterpret_cast<f32x4*>(ob));
    __builtin_nontemporal_store(v1, reinterpret_cast<f32x4*>(ob + 4));
  }
}

// ---------------------------------------------------------------------------
// Fallback (native layout, f32), only if ws can't hold vidP.
// ---------------------------------------------------------------------------
__global__ __launch_bounds__(448) void wpsum_fallback_kernel(
    const float* __restrict__ vid,
    const float* __restrict__ dists,
    const int*   __restrict__ inds,
    float*       __restrict__ out) {
  const int q   = blockIdx.x;
  const int tid = threadIdx.x;

  __shared__ int   s_off[HD_][K_];
  __shared__ float s_w[HD_][K_];
  if (tid < HD_ * K_) {
    const int hd = tid / K_, k = tid % K_;
    const int* ip = inds + (((size_t)hd * Q_ + q) * KTOT_ + k) * 3;
    s_off[hd][k] = ((ip[0] * C_ + hd * CH_) * H_ + ip[1]) * W_ + ip[2];
    s_w[hd][k]   = dists[((size_t)hd * Q_ + q) * KTOT_ + k];
  }
  __syncthreads();

  const int lane = tid & 63;
  const int pi   = tid >> 6;
  const int hd   = lane >> 4;
  const int c    = lane & 15;

  float wk[K_]; int off[K_];
  #pragma unroll
  for (int k = 0; k < K_; ++k) {
    wk[k]  = s_w[hd][k];
    off[k] = s_off[hd][k] + c * HW_;
  }
  #pragma unroll
  for (int pj = 0; pj < PS_; ++pj) {
    const int d = pi * W_ + pj;
    float acc = 0.f;
    #pragma unroll
    for (int k = 0; k < K_; ++k)
      acc = fmaf(wk[k], vid[(size_t)(off[k] + d)], acc);
    out[((size_t)q * (PS_ * PS_) + pi * PS_ + pj) * (HD_ * CH_) + lane] = acc;
  }
}

// ---------------------------------------------------------------------------
extern "C" void kernel_launch(void* const* d_in, const int* in_sizes, int n_in,
                              void* d_out, int out_size, void* d_ws, size_t ws_size,
                              hipStream_t stream) {
  const float* vid   = (const float*)d_in[0];
  const float* dists = (const float*)d_in[1];
  const int*   inds  = (const int*)d_in[2];
  float*       out   = (float*)d_out;

  const size_t need = (size_t)HD_ * T_ * HW_ * CH_ * sizeof(__half);  // 64 MiB
  if (ws_size >= need) {
    __half* vidP = (__half*)d_ws;
    transcvt_kernel<<<T_ * H_ * (W_ / 64), 256, 0, stream>>>(vid, vidP);
    wpsum_h_kernel<<<Q_, 448, 0, stream>>>(vidP, dists, inds, out);
  } else {
    wpsum_fallback_kernel<<<Q_, 448, 0, stream>>>(vid, dists, inds, out);
  }
}